// Round 1
// baseline (238.225 us; speedup 1.0000x reference)
//
#include <hip/hip_runtime.h>
#include <math.h>

// InterContactLoss on MI355X.
// Structure:
//   ws poison -> memset(inf bits) for 4 dmin2 arrays, memset(0) for 8 accumulators
//   4x mindist_kernel: min_j ||a_i - b_j||^2 (register rowmin, LDS-staged B,
//                      B-loop split across blockIdx.z, combined via uint atomicMin)
//   2x reduce_loss:    per-element BCE/Huber terms -> block reduce -> atomicAdd
//   1x finalize:       balanced-BCE weighting + masked-Huber means -> scalar
//
// min over d^2, sqrt deferred to the 143K reduced values (monotone).

#define BT 16
#define VH 6890
#define VO 2048
#define CHUNK 1024   // B verts staged per LDS chunk (12 KB)

template<int R>
__global__ __launch_bounds__(256)
void mindist_kernel(const float* __restrict__ A, const float* __restrict__ B,
                    unsigned int* __restrict__ outMin, int nA, int nB, int sliceLen)
{
    __shared__ float lds[3 * CHUNK];
    const int bt  = blockIdx.y;
    const int tid = threadIdx.x;
    const int a0  = blockIdx.x * (256 * R) + tid;
    const float* Ab = A + (size_t)bt * nA * 3;
    const float* Bb = B + (size_t)bt * nB * 3;

    float ax[R], ay[R], az[R], rmin[R];
#pragma unroll
    for (int m = 0; m < R; ++m) {
        int a = a0 + 256 * m;
        int ai = (a < nA) ? a : 0;          // clamped load; result never stored
        ax[m] = Ab[ai * 3 + 0];
        ay[m] = Ab[ai * 3 + 1];
        az[m] = Ab[ai * 3 + 2];
        rmin[m] = 3.4e38f;
    }

    const int b_lo = blockIdx.z * sliceLen;
    const int b_hi = min(nB, b_lo + sliceLen);

    for (int c0 = b_lo; c0 < b_hi; c0 += CHUNK) {
        const int cnt = min(CHUNK, b_hi - c0);
        const int nf  = 3 * cnt;
        __syncthreads();
        const float* src = Bb + 3 * (size_t)c0;
        for (int f = tid; f < nf; f += 256) lds[f] = src[f];   // coalesced stage
        __syncthreads();

#pragma unroll 4
        for (int j = 0; j < cnt; ++j) {
            // uniform address across wave -> LDS broadcast, no bank conflicts
            float bx = lds[3 * j + 0];
            float by = lds[3 * j + 1];
            float bz = lds[3 * j + 2];
#pragma unroll
            for (int m = 0; m < R; ++m) {
                float dx = ax[m] - bx;
                float dy = ay[m] - by;
                float dz = az[m] - bz;
                float d2 = fmaf(dx, dx, fmaf(dy, dy, dz * dz));
                rmin[m] = fminf(rmin[m], d2);
            }
        }
    }

#pragma unroll
    for (int m = 0; m < R; ++m) {
        int a = a0 + 256 * m;
        if (a < nA) {
            // d2 >= 0 -> float bits are order-preserving as uint
            atomicMin(&outMin[(size_t)bt * nA + a], __float_as_uint(rmin[m]));
        }
    }
}

// Per-element loss terms. acc: [pos_count, sum_bce_pos, sum_bce_neg, sum_huber_masked]
__global__ __launch_bounds__(256)
void reduce_loss(const float* __restrict__ pred2, const float* __restrict__ gt2,
                 int N, float* __restrict__ acc)
{
    int i = blockIdx.x * 256 + threadIdx.x;
    float t = 0.f, sp = 0.f, sn = 0.f, sh = 0.f;
    if (i < N) {
        float d  = sqrtf(pred2[i]);
        float dg = sqrtf(gt2[i]);
        float tt = (dg < 0.2f) ? 1.f : 0.f;

        float z = (0.2f - d) * 100.0f;            // (DIST_THR - d) / ALPHA
        float p = 1.0f / (1.0f + expf(-z));
        p = fminf(fmaxf(p, 1e-6f), 1.0f - 1e-6f); // clip like the reference
        float bce = (tt > 0.5f) ? -logf(p) : -logf(1.0f - p);

        float over = fmaxf(d - 0.1f, 0.0f);       // d - CONTACT_TGT
        float hub  = (over < 0.01f) ? (0.5f * over * over) / 0.01f
                                    : (over - 0.5f * 0.01f);
        t  = tt;
        sp = tt * bce;
        sn = (1.0f - tt) * bce;
        sh = tt * hub;
    }
    // wave(64) reduce
    for (int off = 32; off > 0; off >>= 1) {
        t  += __shfl_down(t,  off);
        sp += __shfl_down(sp, off);
        sn += __shfl_down(sn, off);
        sh += __shfl_down(sh, off);
    }
    __shared__ float wsum[4][4];
    int wid = threadIdx.x >> 6, lane = threadIdx.x & 63;
    if (lane == 0) {
        wsum[wid][0] = t; wsum[wid][1] = sp; wsum[wid][2] = sn; wsum[wid][3] = sh;
    }
    __syncthreads();
    if (threadIdx.x == 0) {
        float a = 0, b = 0, c = 0, d = 0;
        for (int w = 0; w < 4; ++w) {
            a += wsum[w][0]; b += wsum[w][1]; c += wsum[w][2]; d += wsum[w][3];
        }
        atomicAdd(&acc[0], a);
        atomicAdd(&acc[1], b);
        atomicAdd(&acc[2], c);
        atomicAdd(&acc[3], d);
    }
}

__global__ void finalize_kernel(const float* __restrict__ acc, float* __restrict__ out)
{
    float Ph = acc[0], SpH = acc[1], SnH = acc[2], ShH = acc[3];
    float Po = acc[4], SpO = acc[5], SnO = acc[6], ShO = acc[7];
    const float Nh = (float)(BT * VH);
    const float No = (float)(BT * VO);

    float pwH = ((Nh - Ph) + 1e-6f) / (Ph + 1e-6f);
    float pwO = ((No - Po) + 1e-6f) / (Po + 1e-6f);
    float bceH = (pwH * SpH + SnH) / Nh;   // mean(w * bce)
    float bceO = (pwO * SpO + SnO) / No;
    float Lbce = 0.5f * (bceH + bceO);

    float LdH = (Ph > 0.f) ? ShH / fmaxf(Ph, 1.f) : 0.f;
    float LdO = (Po > 0.f) ? ShO / fmaxf(Po, 1.f) : 0.f;
    float Ldist = LdH + LdO;

    out[0] = 0.5f * Lbce + 1.0f * Ldist;   // W_BCE * L_bce + W_DIST * L_dist
}

extern "C" void kernel_launch(void* const* d_in, const int* in_sizes, int n_in,
                              void* d_out, int out_size, void* d_ws, size_t ws_size,
                              hipStream_t stream)
{
    const float* hv  = (const float*)d_in[0];   // human_verts      [16,6890,3]
    const float* ov  = (const float*)d_in[1];   // object_verts     [16,2048,3]
    const float* ghv = (const float*)d_in[2];   // gt_human_verts
    const float* gov = (const float*)d_in[3];   // gt_object_verts

    float* ws  = (float*)d_ws;
    float* dh  = ws;                 // [16*6890] min d^2 human->object
    float* dov = dh  + BT * VH;      // [16*2048] min d^2 object->human
    float* dhg = dov + BT * VO;      // gt versions
    float* dog = dhg + BT * VH;
    float* acc = dog + BT * VO;      // 8 accumulators

    const size_t minFloats = 2 * ((size_t)BT * VH + (size_t)BT * VO);
    // 0x7f7f7f7f as float = 3.39e38 > any d^2; order-preserving init for uint atomicMin
    hipMemsetAsync(ws, 0x7f, minFloats * sizeof(float), stream);
    hipMemsetAsync(acc, 0, 8 * sizeof(float), stream);

    // human-owned passes: R=4 (1024 verts/block), B-loop split 4 ways -> 448 blocks
    mindist_kernel<4><<<dim3(7, BT, 4), 256, 0, stream>>>(hv,  ov,  (unsigned int*)dh,  VH, VO, 512);
    mindist_kernel<4><<<dim3(7, BT, 4), 256, 0, stream>>>(ghv, gov, (unsigned int*)dhg, VH, VO, 512);
    // object-owned passes: R=2 (512 verts/block), B-loop split 8 ways -> 512 blocks
    mindist_kernel<2><<<dim3(4, BT, 8), 256, 0, stream>>>(ov,  hv,  (unsigned int*)dov, VO, VH, 862);
    mindist_kernel<2><<<dim3(4, BT, 8), 256, 0, stream>>>(gov, ghv, (unsigned int*)dog, VO, VH, 862);

    reduce_loss<<<dim3((BT * VH + 255) / 256), 256, 0, stream>>>(dh,  dhg, BT * VH, acc + 0);
    reduce_loss<<<dim3((BT * VO + 255) / 256), 256, 0, stream>>>(dov, dog, BT * VO, acc + 4);

    finalize_kernel<<<1, 1, 0, stream>>>(acc, (float*)d_out);
}

// Round 2
// 163.608 us; speedup vs baseline: 1.4561x; 1.4561x over previous
//
#include <hip/hip_runtime.h>
#include <math.h>

// InterContactLoss on MI355X — round 2.
//
// Key changes vs round 1 (which was VALU-issue-bound, 87% VALUBusy, 42.5us/pass):
//  - expanded form: min_j ||a-b||^2 = aa + min_j(bb - 2 a.b). LDS stages
//    [-2bx,-2by,-2bz,bb] per B vert -> inner loop = 3 fma + 1 min per pair
//    (reference also uses the expanded form).
//  - packed fp32: rows processed as float2 ext-vectors so the backend can emit
//    v_pk_fma_f32 (full-rate packed fp32 on gfx950) -> 3 pk_fma per 2 pairs.
//  - ONE fused mindist launch for all 4 direction/pred-gt passes (2048 blocks,
//    8 waves/SIMD), ds_read_b128 B-reads, pad-to-uniform j loops.
//  - launches: 2 memset + mindist + reduce + finalize = 5 (was 9).

#define BT 16
#define VH 6890
#define VO 2048
#define NH (BT * VH)   // 110240
#define NO (BT * VO)   // 32768

typedef float v2f __attribute__((ext_vector_type(2)));

#define RP 4           // packed row-pairs per thread (8 rows)

__global__ __launch_bounds__(256, 4)
void mindist_all(const float* __restrict__ hv,  const float* __restrict__ ov,
                 const float* __restrict__ ghv, const float* __restrict__ gov,
                 unsigned int* __restrict__ dh,  unsigned int* __restrict__ dov,
                 unsigned int* __restrict__ dhg, unsigned int* __restrict__ dog)
{
    __shared__ float4 lds[256];   // staged B: [-2bx,-2by,-2bz,bb], max 256 entries (4KB)

    const int idx = blockIdx.x;
    const float *A, *B;
    unsigned int* out;
    int nA, nB, bt, abk, sliceLen, b0;

    if (idx < 1024) {
        // human-owned: rows = human verts (6890, 4 blocks of 2048), B = object (2048, 8 slices of 256)
        const int p = idx >> 9;           // 0 = pred, 1 = gt
        const int r = idx & 511;
        abk = r & 3;
        bt  = (r >> 2) & 15;
        const int z = r >> 6;             // 0..7
        A = p ? ghv : hv;  B = p ? gov : ov;  out = p ? dhg : dh;
        nA = VH; nB = VO; sliceLen = 256; b0 = z * 256;
    } else {
        // object-owned: rows = object verts (2048, 1 block), B = human (6890 -> 32 slices of 216, padded)
        const int q = idx - 1024;
        const int p = q >> 9;
        const int r = q & 511;
        abk = 0;
        bt  = r & 15;
        const int z = r >> 4;             // 0..31
        A = p ? gov : ov;  B = p ? ghv : hv;  out = p ? dog : dov;
        nA = VO; nB = VH; sliceLen = 216; b0 = z * 216;
    }

    const float* Ab = A + (size_t)bt * nA * 3;
    const float* Bb = B + (size_t)bt * nB * 3;
    const int tid = threadIdx.x;

    // stage this block's B slice: w = [-2bx, -2by, -2bz, bx^2+by^2+bz^2]; pad with bb=+huge
    if (tid < sliceLen) {
        const int gj = b0 + tid;
        float4 w;
        if (gj < nB) {
            const float bx = Bb[gj * 3 + 0];
            const float by = Bb[gj * 3 + 1];
            const float bz = Bb[gj * 3 + 2];
            w = make_float4(-2.f * bx, -2.f * by, -2.f * bz,
                            fmaf(bx, bx, fmaf(by, by, bz * bz)));
        } else {
            w = make_float4(0.f, 0.f, 0.f, 3.0e38f);
        }
        lds[tid] = w;
    }

    // A rows: row(m) = abk*2048 + tid + m*256, packed as (2k, 2k+1)
    const int rowb = abk * 2048 + tid;
    v2f ax[RP], ay[RP], az[RP], rmin[RP];
#pragma unroll
    for (int k = 0; k < RP; ++k) {
        const int r0 = rowb + (2 * k    ) * 256;
        const int r1 = rowb + (2 * k + 1) * 256;
        const int i0 = (r0 < nA) ? r0 : 0;   // clamped load; result never stored
        const int i1 = (r1 < nA) ? r1 : 0;
        ax[k] = (v2f){Ab[i0 * 3 + 0], Ab[i1 * 3 + 0]};
        ay[k] = (v2f){Ab[i0 * 3 + 1], Ab[i1 * 3 + 1]};
        az[k] = (v2f){Ab[i0 * 3 + 2], Ab[i1 * 3 + 2]};
        rmin[k] = (v2f){3.0e38f, 3.0e38f};
    }

    __syncthreads();

    // inner: t = fma(ax,-2bx, fma(ay,-2by, fma(az,-2bz, bb))); rmin = min(rmin, t)
    for (int j = 0; j < sliceLen; j += 4) {
#pragma unroll
        for (int u = 0; u < 4; ++u) {
            const float4 b = lds[j + u];          // uniform addr -> broadcast, b128 read
            const v2f nbx = (v2f){b.x, b.x};
            const v2f nby = (v2f){b.y, b.y};
            const v2f nbz = (v2f){b.z, b.z};
            const v2f bbv = (v2f){b.w, b.w};
#pragma unroll
            for (int k = 0; k < RP; ++k) {
                v2f t = __builtin_elementwise_fma(az[k], nbz, bbv);
                t     = __builtin_elementwise_fma(ay[k], nby, t);
                t     = __builtin_elementwise_fma(ax[k], nbx, t);
                rmin[k] = __builtin_elementwise_min(rmin[k], t);
            }
        }
    }

    // epilogue: d2 = max(aa + rmin, 0); combine across z-slices via uint atomicMin
#pragma unroll
    for (int k = 0; k < RP; ++k) {
        const int r0 = rowb + (2 * k    ) * 256;
        const int r1 = rowb + (2 * k + 1) * 256;
        if (r0 < nA) {
            const float aa = fmaf(ax[k].x, ax[k].x, fmaf(ay[k].x, ay[k].x, az[k].x * az[k].x));
            const float v  = fmaxf(aa + rmin[k].x, 0.f);
            atomicMin(&out[(size_t)bt * nA + r0], __float_as_uint(v));
        }
        if (r1 < nA) {
            const float aa = fmaf(ax[k].y, ax[k].y, fmaf(ay[k].y, ay[k].y, az[k].y * az[k].y));
            const float v  = fmaxf(aa + rmin[k].y, 0.f);
            atomicMin(&out[(size_t)bt * nA + r1], __float_as_uint(v));
        }
    }
}

// Per-element loss terms over both segments.
// acc layout: [0..3] human: {pos_count, sum_bce_pos, sum_bce_neg, sum_huber_masked}; [4..7] object.
#define NBLK_H 431   // ceil(110240/256)
#define NBLK_O 128   // 32768/256

__global__ __launch_bounds__(256)
void reduce_loss_all(const float* __restrict__ dh2, const float* __restrict__ dhg2,
                     const float* __restrict__ do2, const float* __restrict__ dog2,
                     float* __restrict__ acc)
{
    const int b = blockIdx.x;
    const float *p2, *g2;
    float* a4;
    int N, i0;
    if (b < NBLK_H) { p2 = dh2; g2 = dhg2; a4 = acc;     N = NH; i0 = b * 256; }
    else            { p2 = do2; g2 = dog2; a4 = acc + 4; N = NO; i0 = (b - NBLK_H) * 256; }

    const int i = i0 + threadIdx.x;
    float t = 0.f, sp = 0.f, sn = 0.f, sh = 0.f;
    if (i < N) {
        const float d  = sqrtf(p2[i]);
        const float dg = sqrtf(g2[i]);
        const float tt = (dg < 0.2f) ? 1.f : 0.f;

        const float z = (0.2f - d) * 100.0f;           // (DIST_THR - d) / ALPHA
        float p = 1.0f / (1.0f + expf(-z));
        p = fminf(fmaxf(p, 1e-6f), 1.0f - 1e-6f);
        const float bce = (tt > 0.5f) ? -logf(p) : -logf(1.0f - p);

        const float over = fmaxf(d - 0.1f, 0.0f);      // d - CONTACT_TGT
        const float hub  = (over < 0.01f) ? (0.5f * over * over) / 0.01f
                                          : (over - 0.5f * 0.01f);
        t  = tt;
        sp = tt * bce;
        sn = (1.0f - tt) * bce;
        sh = tt * hub;
    }
    for (int off = 32; off > 0; off >>= 1) {
        t  += __shfl_down(t,  off);
        sp += __shfl_down(sp, off);
        sn += __shfl_down(sn, off);
        sh += __shfl_down(sh, off);
    }
    __shared__ float wsum[4][4];
    const int wid = threadIdx.x >> 6, lane = threadIdx.x & 63;
    if (lane == 0) {
        wsum[wid][0] = t; wsum[wid][1] = sp; wsum[wid][2] = sn; wsum[wid][3] = sh;
    }
    __syncthreads();
    if (threadIdx.x == 0) {
        float s0 = 0, s1 = 0, s2 = 0, s3 = 0;
        for (int w = 0; w < 4; ++w) {
            s0 += wsum[w][0]; s1 += wsum[w][1]; s2 += wsum[w][2]; s3 += wsum[w][3];
        }
        atomicAdd(&a4[0], s0);
        atomicAdd(&a4[1], s1);
        atomicAdd(&a4[2], s2);
        atomicAdd(&a4[3], s3);
    }
}

__global__ void finalize_kernel(const float* __restrict__ acc, float* __restrict__ out)
{
    const float Ph = acc[0], SpH = acc[1], SnH = acc[2], ShH = acc[3];
    const float Po = acc[4], SpO = acc[5], SnO = acc[6], ShO = acc[7];
    const float Nh = (float)NH;
    const float No = (float)NO;

    const float pwH = ((Nh - Ph) + 1e-6f) / (Ph + 1e-6f);
    const float pwO = ((No - Po) + 1e-6f) / (Po + 1e-6f);
    const float bceH = (pwH * SpH + SnH) / Nh;   // mean(w * bce)
    const float bceO = (pwO * SpO + SnO) / No;
    const float Lbce = 0.5f * (bceH + bceO);

    const float LdH = (Ph > 0.f) ? ShH / fmaxf(Ph, 1.f) : 0.f;
    const float LdO = (Po > 0.f) ? ShO / fmaxf(Po, 1.f) : 0.f;
    const float Ldist = LdH + LdO;

    out[0] = 0.5f * Lbce + 1.0f * Ldist;
}

extern "C" void kernel_launch(void* const* d_in, const int* in_sizes, int n_in,
                              void* d_out, int out_size, void* d_ws, size_t ws_size,
                              hipStream_t stream)
{
    const float* hv  = (const float*)d_in[0];
    const float* ov  = (const float*)d_in[1];
    const float* ghv = (const float*)d_in[2];
    const float* gov = (const float*)d_in[3];

    float* ws  = (float*)d_ws;
    float* dh  = ws;               // [NH] min d^2 human->object
    float* dov = dh  + NH;         // [NO]
    float* dhg = dov + NO;         // [NH] gt
    float* dog = dhg + NH;         // [NO] gt
    float* acc = dog + NO;         // [8]

    // 0x7f7f7f7f = 3.3966e38f: > any clamped d^2, order-preserving uint init
    hipMemsetAsync(ws, 0x7f, (size_t)(2 * (NH + NO)) * sizeof(float), stream);
    hipMemsetAsync(acc, 0, 8 * sizeof(float), stream);

    mindist_all<<<2048, 256, 0, stream>>>(hv, ov, ghv, gov,
                                          (unsigned int*)dh, (unsigned int*)dov,
                                          (unsigned int*)dhg, (unsigned int*)dog);

    reduce_loss_all<<<NBLK_H + NBLK_O, 256, 0, stream>>>(dh, dhg, dov, dog, acc);

    finalize_kernel<<<1, 1, 0, stream>>>(acc, (float*)d_out);
}